// Round 4
// baseline (158.904 us; speedup 1.0000x reference)
//
#include <hip/hip_runtime.h>
#include <hip/hip_fp16.h>

// ---------- small vector helpers ----------
struct V3 { float x, y, z; };

__device__ __forceinline__ V3 v3add(V3 a, V3 b){ return {a.x+b.x, a.y+b.y, a.z+b.z}; }
__device__ __forceinline__ V3 v3sub(V3 a, V3 b){ return {a.x-b.x, a.y-b.y, a.z-b.z}; }
__device__ __forceinline__ V3 v3scale(V3 a, float s){ return {a.x*s, a.y*s, a.z*s}; }
__device__ __forceinline__ V3 v3mul(V3 a, V3 b){ return {a.x*b.x, a.y*b.y, a.z*b.z}; }
__device__ __forceinline__ float dot3(V3 a, V3 b){ return fmaf(a.x,b.x, fmaf(a.y,b.y, a.z*b.z)); }
__device__ __forceinline__ V3 nrm3(V3 a){
    float s = rsqrtf(fmaxf(dot3(a,a), 1e-20f));
    return v3scale(a, s);
}

// ---------- full q10 quad pyramid layout (texel-count offsets) ----------
#define OFF0 0
#define OFF1 1572864
#define OFF2 1966080
#define OFF3 2064384
#define OFF4 2088960
#define OFF5 2095104
#define DIFF_OFF 2096640
#define SPEC_DIFF_COUNT 2098176
#define FG_OFF 2098176
#define TOTAL_QUADS 2163712
#define WS_BYTES_Q ((size_t)TOTAL_QUADS * 16)   // 34,619,392

// pack thread counts (4 quads per thread)
#define PQ4_SPEC (SPEC_DIFF_COUNT/4)   // 524,544
#define PQ4_FG   (65536/4)             // 16,384
#define PQ4_TOTAL (PQ4_SPEC + PQ4_FG)  // 540,928

// ---------- cube face / uv ----------
__device__ __forceinline__ void cube_face_uv(V3 d, int& face, float& u, float& v){
    float ax = fabsf(d.x), ay = fabsf(d.y), az = fabsf(d.z);
    bool is_x = (ax >= ay) && (ax >= az);
    bool is_y = (!is_x) && (ay >= az);
    face = is_x ? (d.x >= 0.f ? 0 : 1)
                : (is_y ? (d.y >= 0.f ? 2 : 3)
                        : (d.z >= 0.f ? 4 : 5));
    float ma = fmaxf(is_x ? ax : (is_y ? ay : az), 1e-20f);
    float un = (face == 0) ? -d.z : (face == 1) ? d.z : (face == 5) ? -d.x : d.x;
    float vn = (face == 2) ?  d.z : (face == 3) ? -d.z : -d.y;
    float inv = 1.0f / ma;
    u = un * inv;
    v = vn * inv;
}

// ---------- bilinear coords ----------
__device__ __forceinline__ void quad_coord_cube(float u, float v, int R,
                                                int& xq, int& yq, float& fx, float& fy){
    float Rf = (float)R;
    float tu = fmaf(fmaf(u, 0.5f, 0.5f), Rf, -0.5f);
    float tv = fmaf(fmaf(v, 0.5f, 0.5f), Rf, -0.5f);
    float x0f = floorf(tu), y0f = floorf(tv);
    fx = tu - x0f; fy = tv - y0f;
    int x0 = (int)x0f, y0 = (int)y0f;
    fx = (x0 < 0) ? 0.f : fx;
    fy = (y0 < 0) ? 0.f : fy;
    xq = min(max(x0, 0), R-1);
    yq = min(max(y0, 0), R-1);
}

__device__ __forceinline__ void quad_coord_2d(float u, float v, int W, int H,
                                              int& xq, int& yq, float& fx, float& fy){
    float tu = fmaf(u, (float)W, -0.5f);
    float tv = fmaf(v, (float)H, -0.5f);
    float x0f = floorf(tu), y0f = floorf(tv);
    fx = tu - x0f; fy = tv - y0f;
    int x0 = (int)x0f, y0 = (int)y0f;
    fx = (x0 < 0) ? 0.f : fx;
    fy = (y0 < 0) ? 0.f : fy;
    xq = min(max(x0, 0), W-1);
    yq = min(max(y0, 0), H-1);
}

// ---------- q10 blend (4 packed texels: 00,01,10,11) ----------
__device__ __forceinline__ V3 q10_blend(uint4 q, float fx, float fy){
    float w00 = (1.f-fx)*(1.f-fy), w01 = fx*(1.f-fy);
    float w10 = (1.f-fx)*fy,       w11 = fx*fy;
    float r = (float)(q.x & 1023u)*w00 + (float)(q.y & 1023u)*w01
            + (float)(q.z & 1023u)*w10 + (float)(q.w & 1023u)*w11;
    float g = (float)((q.x>>10) & 1023u)*w00 + (float)((q.y>>10) & 1023u)*w01
            + (float)((q.z>>10) & 1023u)*w10 + (float)((q.w>>10) & 1023u)*w11;
    float b = (float)((q.x>>20) & 1023u)*w00 + (float)((q.y>>20) & 1023u)*w01
            + (float)((q.z>>20) & 1023u)*w10 + (float)((q.w>>20) & 1023u)*w11;
    const float s = 1.0f/1023.0f;
    return { r*s, g*s, b*s };
}

__device__ __forceinline__ void q10_fg(uint4 q, float fx, float fy,
                                       float& fa, float& fb){
    float w00 = (1.f-fx)*(1.f-fy), w01 = fx*(1.f-fy);
    float w10 = (1.f-fx)*fy,       w11 = fx*fy;
    float a00 = (float)(q.x & 1023u),        b00 = (float)((q.x>>10) & 1023u);
    float a01 = (float)((q.x>>20) & 1023u),  b01 = (float)(q.y & 1023u);
    float a10 = (float)((q.y>>10) & 1023u),  b10 = (float)((q.y>>20) & 1023u);
    float a11 = (float)(q.z & 1023u),        b11 = (float)((q.z>>10) & 1023u);
    const float s = 1.0f/1023.0f;
    fa = (a00*w00 + a01*w01 + a10*w10 + a11*w11) * s;
    fb = (b00*w00 + b01*w01 + b10*w10 + b11*w11) * s;
}

// ---------- raw f32 bilinear (fallback only) ----------
__device__ __forceinline__ V3 bilinear_cube3(const float* __restrict__ tex, int R,
                                             int face, float u, float v){
    float Rf = (float)R;
    float tu = fmaf(fmaf(u, 0.5f, 0.5f), Rf, -0.5f);
    float tv = fmaf(fmaf(v, 0.5f, 0.5f), Rf, -0.5f);
    float x0 = floorf(tu), y0 = floorf(tv);
    float fx = tu - x0,    fy = tv - y0;
    int x0i = min(max((int)x0,     0), R-1);
    int x1i = min(max((int)x0 + 1, 0), R-1);
    int y0i = min(max((int)y0,     0), R-1);
    int y1i = min(max((int)y0 + 1, 0), R-1);
    const float* base = tex + (size_t)face * R * R * 3;
    const float* r0 = base + (size_t)y0i * R * 3;
    const float* r1 = base + (size_t)y1i * R * 3;
    float a0 = r0[3*x0i], a1 = r0[3*x0i+1], a2 = r0[3*x0i+2];
    float b0 = r0[3*x1i], b1 = r0[3*x1i+1], b2 = r0[3*x1i+2];
    float d0 = r1[3*x0i], d1 = r1[3*x0i+1], d2 = r1[3*x0i+2];
    float e0 = r1[3*x1i], e1 = r1[3*x1i+1], e2 = r1[3*x1i+2];
    float w00 = (1.f-fx)*(1.f-fy), w01 = fx*(1.f-fy);
    float w10 = (1.f-fx)*fy,       w11 = fx*fy;
    V3 out;
    out.x = a0*w00 + b0*w01 + d0*w10 + e0*w11;
    out.y = a1*w00 + b1*w01 + d1*w10 + e1*w11;
    out.z = a2*w00 + b2*w01 + d2*w10 + e2*w11;
    return out;
}

__device__ __forceinline__ void sample_fg(const float* __restrict__ lut,
                                          float u, float v, float& fa, float& fb){
    const int W = 256, H = 256;
    float tu = fmaf(u, (float)W, -0.5f);
    float tv = fmaf(v, (float)H, -0.5f);
    float x0 = floorf(tu), y0 = floorf(tv);
    float fx = tu - x0,    fy = tv - y0;
    int x0i = min(max((int)x0,     0), W-1);
    int x1i = min(max((int)x0 + 1, 0), W-1);
    int y0i = min(max((int)y0,     0), H-1);
    int y1i = min(max((int)y0 + 1, 0), H-1);
    const float2* l2 = (const float2*)lut;
    float2 a = l2[(size_t)y0i*W + x0i];
    float2 b = l2[(size_t)y0i*W + x1i];
    float2 d = l2[(size_t)y1i*W + x0i];
    float2 e = l2[(size_t)y1i*W + x1i];
    float w00 = (1.f-fx)*(1.f-fy), w01 = fx*(1.f-fy);
    float w10 = (1.f-fx)*fy,       w11 = fx*fy;
    fa = a.x*w00 + b.x*w01 + d.x*w10 + e.x*w11;
    fb = a.y*w00 + b.y*w01 + d.y*w10 + e.y*w11;
}

// ---------- linear -> srgb ----------
__device__ __forceinline__ float lin2srgb(float x){
    float xs = (x > 0.0031308f) ? x : 1.0f;
    float p  = __builtin_amdgcn_exp2f(__builtin_amdgcn_logf(xs) * (1.0f/2.4f));
    return (x > 0.0031308f) ? fmaf(1.055f, p, -0.055f) : 12.92f * x;
}

__device__ __forceinline__ float clamp01(float x){ return fminf(fmaxf(x, 0.f), 1.f); }

// ---------- per-pixel precomputed state ----------
struct PixPre {
    V3 diff_alb, spec_alb;
    int sface; float su, sv;
    int dface; float du, dv;
    int offA, RA, offB, RB; float f;
    float ndotv, rough;
};

__device__ __forceinline__ PixPre pre_pixel_v(V3 pos, V3 nrm, V3 bc, float m, float r, V3 vp)
{
    V3 wo = nrm3(v3sub(vp, pos));
    float ndv_raw = dot3(wo, nrm);
    V3 refl = nrm3(v3sub(v3scale(nrm, 2.0f*ndv_raw), wo));

    PixPre p;
    float one_m = 1.0f - m;
    p.diff_alb = v3scale(bc, one_m);
    p.spec_alb = { fmaf(m, bc.x, 0.04f*one_m),
                   fmaf(m, bc.y, 0.04f*one_m),
                   fmaf(m, bc.z, 0.04f*one_m) };
    p.ndotv = fmaxf(ndv_raw, 0.0001f);
    p.rough = r;

    const float MIN_R = 0.08f, MAX_R = 0.5f;
    float lo = (fminf(fmaxf(r, MIN_R), MAX_R) - MIN_R) / (MAX_R - MIN_R) * 4.0f;
    float hi = (fminf(fmaxf(r, MAX_R), 1.0f) - MAX_R) / (1.0f - MAX_R) + 4.0f;
    float mip = (r < MAX_R) ? lo : hi;
    mip = fminf(fmaxf(mip, 0.0f), 5.0f);
    int l0 = min((int)mip, 5);
    p.f = mip - (float)l0;
    int l1 = min(l0 + 1, 5);

    int offA = OFF0;
    offA = (l0 == 1) ? OFF1 : offA; offA = (l0 == 2) ? OFF2 : offA;
    offA = (l0 == 3) ? OFF3 : offA; offA = (l0 == 4) ? OFF4 : offA;
    offA = (l0 == 5) ? OFF5 : offA;
    int offB = OFF1;
    offB = (l1 == 2) ? OFF2 : offB; offB = (l1 == 3) ? OFF3 : offB;
    offB = (l1 == 4) ? OFF4 : offB; offB = (l1 == 5) ? OFF5 : offB;
    p.offA = offA; p.RA = 512 >> l0;
    p.offB = offB; p.RB = 512 >> l1;

    cube_face_uv(nrm, p.dface, p.du, p.dv);
    cube_face_uv(refl, p.sface, p.su, p.sv);
    return p;
}

// ---------- q10 pack helper ----------
__device__ __forceinline__ unsigned pk3(float a, float b, float c){
    unsigned ia = __float2uint_rn(fminf(fmaxf(a, 0.f), 1.f) * 1023.f);
    unsigned ib = __float2uint_rn(fminf(fmaxf(b, 0.f), 1.f) * 1023.f);
    unsigned ic = __float2uint_rn(fminf(fmaxf(c, 0.f), 1.f) * 1023.f);
    return ia | (ib << 10) | (ic << 20);
}

// ---------- vectorized full-pyramid pack: 4 quads per thread ----------
// All region boundaries and all R are multiples of 4, so a 4-quad group never crosses
// a region or row boundary. 3*local floats with local % 4 == 0 -> 48B-aligned float4s.
__global__ __launch_bounds__(256)
void pack_q10f(const float* __restrict__ s0, const float* __restrict__ s1,
               const float* __restrict__ s2, const float* __restrict__ s3,
               const float* __restrict__ s4, const float* __restrict__ s5,
               const float* __restrict__ diffuse, const float* __restrict__ fg_lut,
               uint4* __restrict__ qws)
{
    int t = blockIdx.x * blockDim.x + threadIdx.x;
    if (t >= PQ4_TOTAL) return;

    if (t >= PQ4_SPEC) {
        // fg region: 4 quads along a row. texels x..x+4 of rows y and min(y+1,255).
        int local = (t - PQ4_SPEC) * 4;
        int x = local & 255, y = local >> 8;
        int y1 = (y == 255) ? y : y + 1;
        const float* r0p = fg_lut + 2*local;
        const float* r1p = fg_lut + 2*((y1 << 8) + x);
        bool edge = (x == 252);
        float4 r0a = ((const float4*)r0p)[0], r0b = ((const float4*)r0p)[1];
        float4 r1a = ((const float4*)r1p)[0], r1b = ((const float4*)r1p)[1];
        float4 r0c = *(const float4*)(r0p + (edge ? 4 : 8));
        float4 r1c = *(const float4*)(r1p + (edge ? 4 : 8));
        float a0[5], b0[5], a1[5], b1[5];
        a0[0]=r0a.x; b0[0]=r0a.y; a0[1]=r0a.z; b0[1]=r0a.w;
        a0[2]=r0b.x; b0[2]=r0b.y; a0[3]=r0b.z; b0[3]=r0b.w;
        a0[4]= edge ? r0b.z : r0c.x; b0[4]= edge ? r0b.w : r0c.y;
        a1[0]=r1a.x; b1[0]=r1a.y; a1[1]=r1a.z; b1[1]=r1a.w;
        a1[2]=r1b.x; b1[2]=r1b.y; a1[3]=r1b.z; b1[3]=r1b.w;
        a1[4]= edge ? r1b.z : r1c.x; b1[4]= edge ? r1b.w : r1c.y;
        #pragma unroll
        for (int k = 0; k < 4; ++k) {
            uint4 q;
            q.x = pk3(a0[k], b0[k], a0[k+1]);
            q.y = pk3(b0[k+1], a1[k], b1[k]);
            q.z = pk3(a1[k+1], b1[k+1], 0.f);
            q.w = 0u;
            qws[(size_t)FG_OFF + local + k] = q;
        }
        return;
    }

    // spec/diffuse quad region (s0..s5 + diffuse): 4 quads along a row
    int local4q = t * 4;
    const float* src; int local; int Rm;
    if      (local4q >= DIFF_OFF) { src = diffuse; local = local4q - DIFF_OFF; Rm = 15;  }
    else if (local4q >= OFF5)     { src = s5;      local = local4q - OFF5;     Rm = 15;  }
    else if (local4q >= OFF4)     { src = s4;      local = local4q - OFF4;     Rm = 31;  }
    else if (local4q >= OFF3)     { src = s3;      local = local4q - OFF3;     Rm = 63;  }
    else if (local4q >= OFF2)     { src = s2;      local = local4q - OFF2;     Rm = 127; }
    else if (local4q >= OFF1)     { src = s1;      local = local4q - OFF1;     Rm = 255; }
    else                          { src = s0;      local = local4q;            Rm = 511; }
    int x = local & Rm;
    int y = (local / (Rm + 1)) & Rm;
    int rowUp = (y == Rm) ? 0 : (Rm + 1);
    const float* r0p = src + 3*local;
    const float* r1p = src + 3*(local + rowUp);
    bool edge = (x + 4 > Rm);
    float4 A0 = ((const float4*)r0p)[0], A1 = ((const float4*)r0p)[1], A2 = ((const float4*)r0p)[2];
    float4 B0 = ((const float4*)r1p)[0], B1 = ((const float4*)r1p)[1], B2 = ((const float4*)r1p)[2];
    float4 A3 = *(const float4*)(r0p + (edge ? 8 : 12));
    float4 B3 = *(const float4*)(r1p + (edge ? 8 : 12));
    unsigned t0[5], t1[5];
    t0[0] = pk3(A0.x, A0.y, A0.z);
    t0[1] = pk3(A0.w, A1.x, A1.y);
    t0[2] = pk3(A1.z, A1.w, A2.x);
    t0[3] = pk3(A2.y, A2.z, A2.w);
    t0[4] = edge ? t0[3] : pk3(A3.x, A3.y, A3.z);
    t1[0] = pk3(B0.x, B0.y, B0.z);
    t1[1] = pk3(B0.w, B1.x, B1.y);
    t1[2] = pk3(B1.z, B1.w, B2.x);
    t1[3] = pk3(B2.y, B2.z, B2.w);
    t1[4] = edge ? t1[3] : pk3(B3.x, B3.y, B3.z);
    #pragma unroll
    for (int k = 0; k < 4; ++k) {
        uint4 q;
        q.x = t0[k];
        q.y = t0[k+1];
        q.z = t1[k];
        q.w = t1[k+1];
        qws[(size_t)local4q + k] = q;
    }
}

// ---------- branchless per-pixel address/state precompute ----------
struct PreOut {
    V3 dalb, salb; float f;
    unsigned iF, iA, iB, iD;
    float fAx, fAy, fBx, fBy, fDx, fDy, fFx, fFy;
};

__device__ __forceinline__ unsigned addr_cube(int off, int R, int face, float u, float v,
                                              float& fx, float& fy){
    int x, y;
    quad_coord_cube(u, v, R, x, y, fx, fy);
    return (unsigned)(off + face * R * R + y * R + x);
}

__device__ __forceinline__ PreOut pre_all(V3 pos, V3 nrm, V3 bc, float m, float r, V3 vp){
    PixPre p = pre_pixel_v(pos, nrm, bc, m, r, vp);
    PreOut o;
    o.dalb = p.diff_alb; o.salb = p.spec_alb; o.f = p.f;
    o.iA = addr_cube(p.offA, p.RA, p.sface, p.su, p.sv, o.fAx, o.fAy);
    o.iB = addr_cube(p.offB, p.RB, p.sface, p.su, p.sv, o.fBx, o.fBy);
    o.iD = addr_cube(DIFF_OFF, 16, p.dface, p.du, p.dv, o.fDx, o.fDy);
    int fx_, fy_;
    quad_coord_2d(p.ndotv, p.rough, 256, 256, fx_, fy_, o.fFx, o.fFy);
    o.iF = (unsigned)(FG_OFF + fy_ * 256 + fx_);
    return o;
}

__device__ __forceinline__ void finish_px(const PreOut& p,
                                          uint4 qF, uint4 qA, uint4 qB, uint4 qD,
                                          float* o){
    V3 sA  = q10_blend(qA, p.fAx, p.fAy);
    V3 sB  = q10_blend(qB, p.fBx, p.fBy);
    V3 amb = q10_blend(qD, p.fDx, p.fDy);
    float fa, fb;
    q10_fg(qF, p.fFx, p.fFy, fa, fb);
    V3 spec = { sA.x + (sB.x - sA.x) * p.f,
                sA.y + (sB.y - sA.y) * p.f,
                sA.z + (sB.z - sA.z) * p.f };
    V3 reflc = { fmaf(p.salb.x, fa, fb),
                 fmaf(p.salb.y, fa, fb),
                 fmaf(p.salb.z, fa, fb) };
    V3 rgb = v3add(v3mul(spec, reflc), v3mul(amb, p.dalb));
    o[0] = lin2srgb(clamp01(rgb.x));
    o[1] = lin2srgb(clamp01(rgb.y));
    o[2] = lin2srgb(clamp01(rgb.z));
}

// ---------- main kernel: 2 px/thread, branchless, no LDS, 8-deep gather ILP ----------
__global__ __launch_bounds__(256)
void envlight_q10u(const float* __restrict__ gb_pos,
                   const float* __restrict__ gb_normal,
                   const float* __restrict__ basecolor,
                   const float* __restrict__ metallic,
                   const float* __restrict__ roughness,
                   const float* __restrict__ view_pos,
                   const uint4* __restrict__ qws,
                   float* __restrict__ out,
                   int n)
{
    int t = blockIdx.x * blockDim.x + threadIdx.x;
    int i0 = t * 2;
    if (i0 >= n) return;
    V3 vp = { view_pos[0], view_pos[1], view_pos[2] };

    if (i0 + 1 < n) {
        // i0 % 2 == 0  ->  3*i0 floats is 24B-aligned: 3 aligned float2 per array
        const float2* P = (const float2*)(gb_pos    + 3*i0);
        const float2* N = (const float2*)(gb_normal + 3*i0);
        const float2* B = (const float2*)(basecolor + 3*i0);
        float2 p0 = P[0], p1 = P[1], p2 = P[2];
        float2 n0 = N[0], n1 = N[1], n2 = N[2];
        float2 b0 = B[0], b1 = B[1], b2 = B[2];
        float2 mt = *(const float2*)(metallic  + i0);
        float2 rg = *(const float2*)(roughness + i0);

        // per-pixel state + gather addresses (no branches)
        PreOut A = pre_all({p0.x,p0.y,p1.x}, {n0.x,n0.y,n1.x}, {b0.x,b0.y,b1.x},
                           mt.x, rg.x, vp);
        PreOut Bp = pre_all({p1.y,p2.x,p2.y}, {n1.y,n2.x,n2.y}, {b1.y,b2.x,b2.y},
                            mt.y, rg.y, vp);

        // 8 independent gathers, issued back-to-back
        uint4 aF = qws[A.iF],  aA = qws[A.iA],  aB = qws[A.iB],  aD = qws[A.iD];
        uint4 bF = qws[Bp.iF], bA = qws[Bp.iA], bB = qws[Bp.iB], bD = qws[Bp.iD];

        float of[6];
        finish_px(A,  aF, aA, aB, aD, of);
        finish_px(Bp, bF, bA, bB, bD, of + 3);

        float2* O = (float2*)(out + 3*i0);
        O[0] = make_float2(of[0], of[1]);
        O[1] = make_float2(of[2], of[3]);
        O[2] = make_float2(of[4], of[5]);
    } else {
        int i = i0;
        V3 pos = { gb_pos[3*i],    gb_pos[3*i+1],    gb_pos[3*i+2] };
        V3 nrm = { gb_normal[3*i], gb_normal[3*i+1], gb_normal[3*i+2] };
        V3 bc  = { basecolor[3*i], basecolor[3*i+1], basecolor[3*i+2] };
        PreOut A = pre_all(pos, nrm, bc, metallic[i], roughness[i], vp);
        uint4 aF = qws[A.iF], aA = qws[A.iA], aB = qws[A.iB], aD = qws[A.iD];
        float o[3];
        finish_px(A, aF, aA, aB, aD, o);
        out[3*i+0] = o[0]; out[3*i+1] = o[1]; out[3*i+2] = o[2];
    }
}

// ---------- raw fallback (no workspace) ----------
__global__ __launch_bounds__(256)
void envlight_fallback(const float* __restrict__ gb_pos,
                       const float* __restrict__ gb_normal,
                       const float* __restrict__ basecolor,
                       const float* __restrict__ metallic,
                       const float* __restrict__ roughness,
                       const float* __restrict__ view_pos,
                       const float* __restrict__ diffuse,
                       const float* __restrict__ fg_lut,
                       const float* __restrict__ s0, const float* __restrict__ s1,
                       const float* __restrict__ s2, const float* __restrict__ s3,
                       const float* __restrict__ s4, const float* __restrict__ s5,
                       float* __restrict__ out, int n)
{
    int i = blockIdx.x * blockDim.x + threadIdx.x;
    if (i >= n) return;
    V3 vp = { view_pos[0], view_pos[1], view_pos[2] };
    V3 pos = { gb_pos[3*i],    gb_pos[3*i+1],    gb_pos[3*i+2] };
    V3 nrm = { gb_normal[3*i], gb_normal[3*i+1], gb_normal[3*i+2] };
    V3 bc  = { basecolor[3*i], basecolor[3*i+1], basecolor[3*i+2] };
    PixPre p = pre_pixel_v(pos, nrm, bc, metallic[i], roughness[i], vp);
    int l0 = 0;
    l0 = (p.RA == 256) ? 1 : l0; l0 = (p.RA == 128) ? 2 : l0;
    l0 = (p.RA ==  64) ? 3 : l0; l0 = (p.RA ==  32) ? 4 : l0;
    l0 = (p.RA ==  16) ? 5 : l0;
    int l1 = min(l0 + 1, 5);
    const float* tA = s0;
    tA = (l0 == 1) ? s1 : tA; tA = (l0 == 2) ? s2 : tA;
    tA = (l0 == 3) ? s3 : tA; tA = (l0 == 4) ? s4 : tA; tA = (l0 == 5) ? s5 : tA;
    const float* tB = s0;
    tB = (l1 == 1) ? s1 : tB; tB = (l1 == 2) ? s2 : tB;
    tB = (l1 == 3) ? s3 : tB; tB = (l1 == 4) ? s4 : tB; tB = (l1 == 5) ? s5 : tB;
    V3 ambient = bilinear_cube3(diffuse, 16, p.dface, p.du, p.dv);
    V3 specA   = bilinear_cube3(tA, p.RA, p.sface, p.su, p.sv);
    V3 specB   = bilinear_cube3(tB, p.RB, p.sface, p.su, p.sv);
    float fa, fb;
    sample_fg(fg_lut, p.ndotv, p.rough, fa, fb);
    V3 spec = { specA.x + (specB.x - specA.x) * p.f,
                specA.y + (specB.y - specA.y) * p.f,
                specA.z + (specB.z - specA.z) * p.f };
    V3 reflc = { fmaf(p.spec_alb.x, fa, fb),
                 fmaf(p.spec_alb.y, fa, fb),
                 fmaf(p.spec_alb.z, fa, fb) };
    V3 rgb = v3add(v3mul(spec, reflc), v3mul(ambient, p.diff_alb));
    out[3*i+0] = lin2srgb(clamp01(rgb.x));
    out[3*i+1] = lin2srgb(clamp01(rgb.y));
    out[3*i+2] = lin2srgb(clamp01(rgb.z));
}

extern "C" void kernel_launch(void* const* d_in, const int* in_sizes, int n_in,
                              void* d_out, int out_size, void* d_ws, size_t ws_size,
                              hipStream_t stream) {
    const float* gb_pos    = (const float*)d_in[0];
    const float* gb_normal = (const float*)d_in[1];
    const float* basecolor = (const float*)d_in[2];
    const float* metallic  = (const float*)d_in[3];
    const float* roughness = (const float*)d_in[4];
    const float* view_pos  = (const float*)d_in[5];
    const float* diffuse   = (const float*)d_in[6];
    const float* fg_lut    = (const float*)d_in[7];
    const float* s0        = (const float*)d_in[8];
    const float* s1        = (const float*)d_in[9];
    const float* s2        = (const float*)d_in[10];
    const float* s3        = (const float*)d_in[11];
    const float* s4        = (const float*)d_in[12];
    const float* s5        = (const float*)d_in[13];
    float* out = (float*)d_out;

    int n = in_sizes[0] / 3;
    int block = 256;

    if (ws_size >= WS_BYTES_Q) {
        uint4* qws = (uint4*)d_ws;
        int pgrid = (PQ4_TOTAL + block - 1) / block;
        pack_q10f<<<pgrid, block, 0, stream>>>(s0, s1, s2, s3, s4, s5,
                                               diffuse, fg_lut, qws);
        int t2 = (n + 1) / 2;
        int mgrid = (t2 + block - 1) / block;
        envlight_q10u<<<mgrid, block, 0, stream>>>(gb_pos, gb_normal, basecolor,
            metallic, roughness, view_pos, qws, out, n);
    } else {
        int grid = (n + block - 1) / block;
        envlight_fallback<<<grid, block, 0, stream>>>(gb_pos, gb_normal, basecolor,
            metallic, roughness, view_pos, diffuse, fg_lut,
            s0, s1, s2, s3, s4, s5, out, n);
    }
}

// Round 5
// 151.709 us; speedup vs baseline: 1.0474x; 1.0474x over previous
//
#include <hip/hip_runtime.h>
#include <hip/hip_fp16.h>

// ---------- small vector helpers ----------
struct V3 { float x, y, z; };

__device__ __forceinline__ V3 v3add(V3 a, V3 b){ return {a.x+b.x, a.y+b.y, a.z+b.z}; }
__device__ __forceinline__ V3 v3sub(V3 a, V3 b){ return {a.x-b.x, a.y-b.y, a.z-b.z}; }
__device__ __forceinline__ V3 v3scale(V3 a, float s){ return {a.x*s, a.y*s, a.z*s}; }
__device__ __forceinline__ V3 v3mul(V3 a, V3 b){ return {a.x*b.x, a.y*b.y, a.z*b.z}; }
__device__ __forceinline__ float dot3(V3 a, V3 b){ return fmaf(a.x,b.x, fmaf(a.y,b.y, a.z*b.z)); }
__device__ __forceinline__ V3 nrm3(V3 a){
    float s = rsqrtf(fmaxf(dot3(a,a), 1e-20f));
    return v3scale(a, s);
}

// nontemporal helpers (ext_vector types: __builtin_nontemporal_* needs native vectors)
typedef float vf2 __attribute__((ext_vector_type(2)));
__device__ __forceinline__ vf2 ntload2(const float* p){
    return __builtin_nontemporal_load((const vf2*)p);
}
__device__ __forceinline__ void ntstore2(float* p, float a, float b){
    vf2 v; v.x = a; v.y = b;
    __builtin_nontemporal_store(v, (vf2*)p);
}

// ---------- quad layout (s0 raw-sampled in main; s5/diffuse: LDS appendix only) ----------
//   s1 (R=256): [0, 393216)
//   s2 (R=128): [393216, 491520)
//   s3 (R= 64): [491520, 516096)
//   s4 (R= 32): [516096, 522240)
//   fg  (256²): [522240, 587776)
#define NOFF1 0
#define NOFF2 393216
#define NOFF3 491520
#define NOFF4 516096
#define SPEC4_COUNT 522240
#define NFG_OFF 522240
#define NTOT_QUADS 587776
// appendix: compact 1-uint-per-texel q10 for diffuse(1536) + mip5(1536)
#define APP_DIFF 0
#define APP_M5   1536
#define APP_UINTS 3072
#define WS_BYTES_NEW ((size_t)NTOT_QUADS * 16 + (size_t)APP_UINTS * 4)   // 9,416,704

// pack thread counts (4 quads / 4 texels per thread)
#define NQ4_SPEC (SPEC4_COUNT/4)    // 130,560
#define NQ4_FG   (65536/4)          // 16,384
#define NQ4_APP  (APP_UINTS/4)      // 768
#define NQ4_TOTAL (NQ4_SPEC + NQ4_FG + NQ4_APP)   // 147,712

// ---------- cube face / uv ----------
__device__ __forceinline__ void cube_face_uv(V3 d, int& face, float& u, float& v){
    float ax = fabsf(d.x), ay = fabsf(d.y), az = fabsf(d.z);
    bool is_x = (ax >= ay) && (ax >= az);
    bool is_y = (!is_x) && (ay >= az);
    face = is_x ? (d.x >= 0.f ? 0 : 1)
                : (is_y ? (d.y >= 0.f ? 2 : 3)
                        : (d.z >= 0.f ? 4 : 5));
    float ma = fmaxf(is_x ? ax : (is_y ? ay : az), 1e-20f);
    float un = (face == 0) ? -d.z : (face == 1) ? d.z : (face == 5) ? -d.x : d.x;
    float vn = (face == 2) ?  d.z : (face == 3) ? -d.z : -d.y;
    float inv = 1.0f / ma;
    u = un * inv;
    v = vn * inv;
}

// ---------- bilinear coords ----------
__device__ __forceinline__ void quad_coord_cube(float u, float v, int R,
                                                int& xq, int& yq, float& fx, float& fy){
    float Rf = (float)R;
    float tu = fmaf(fmaf(u, 0.5f, 0.5f), Rf, -0.5f);
    float tv = fmaf(fmaf(v, 0.5f, 0.5f), Rf, -0.5f);
    float x0f = floorf(tu), y0f = floorf(tv);
    fx = tu - x0f; fy = tv - y0f;
    int x0 = (int)x0f, y0 = (int)y0f;
    fx = (x0 < 0) ? 0.f : fx;
    fy = (y0 < 0) ? 0.f : fy;
    xq = min(max(x0, 0), R-1);
    yq = min(max(y0, 0), R-1);
}

__device__ __forceinline__ void quad_coord_2d(float u, float v, int W, int H,
                                              int& xq, int& yq, float& fx, float& fy){
    float tu = fmaf(u, (float)W, -0.5f);
    float tv = fmaf(v, (float)H, -0.5f);
    float x0f = floorf(tu), y0f = floorf(tv);
    fx = tu - x0f; fy = tv - y0f;
    int x0 = (int)x0f, y0 = (int)y0f;
    fx = (x0 < 0) ? 0.f : fx;
    fy = (y0 < 0) ? 0.f : fy;
    xq = min(max(x0, 0), W-1);
    yq = min(max(y0, 0), H-1);
}

// ---------- q10 blend (4 packed texels: 00,01,10,11) ----------
__device__ __forceinline__ V3 q10_blend(uint4 q, float fx, float fy){
    float w00 = (1.f-fx)*(1.f-fy), w01 = fx*(1.f-fy);
    float w10 = (1.f-fx)*fy,       w11 = fx*fy;
    float r = (float)(q.x & 1023u)*w00 + (float)(q.y & 1023u)*w01
            + (float)(q.z & 1023u)*w10 + (float)(q.w & 1023u)*w11;
    float g = (float)((q.x>>10) & 1023u)*w00 + (float)((q.y>>10) & 1023u)*w01
            + (float)((q.z>>10) & 1023u)*w10 + (float)((q.w>>10) & 1023u)*w11;
    float b = (float)((q.x>>20) & 1023u)*w00 + (float)((q.y>>20) & 1023u)*w01
            + (float)((q.z>>20) & 1023u)*w10 + (float)((q.w>>20) & 1023u)*w11;
    const float s = 1.0f/1023.0f;
    return { r*s, g*s, b*s };
}

__device__ __forceinline__ void q10_fg(uint4 q, float fx, float fy,
                                       float& fa, float& fb){
    float w00 = (1.f-fx)*(1.f-fy), w01 = fx*(1.f-fy);
    float w10 = (1.f-fx)*fy,       w11 = fx*fy;
    float a00 = (float)(q.x & 1023u),        b00 = (float)((q.x>>10) & 1023u);
    float a01 = (float)((q.x>>20) & 1023u),  b01 = (float)(q.y & 1023u);
    float a10 = (float)((q.y>>10) & 1023u),  b10 = (float)((q.y>>20) & 1023u);
    float a11 = (float)(q.z & 1023u),        b11 = (float)((q.z>>10) & 1023u);
    const float s = 1.0f/1023.0f;
    fa = (a00*w00 + a01*w01 + a10*w10 + a11*w11) * s;
    fb = (b00*w00 + b01*w01 + b10*w10 + b11*w11) * s;
}

// ---------- LDS compact-q10 bilinear (4-corner clamp) ----------
__device__ __forceinline__ V3 lds_bilin(const unsigned* lds, int base, int R,
                                        int face, float u, float v){
    float Rf = (float)R;
    float tu = fmaf(fmaf(u, 0.5f, 0.5f), Rf, -0.5f);
    float tv = fmaf(fmaf(v, 0.5f, 0.5f), Rf, -0.5f);
    float x0f = floorf(tu), y0f = floorf(tv);
    float fx = tu - x0f, fy = tv - y0f;
    int x0 = min(max((int)x0f,     0), R-1);
    int x1 = min(max((int)x0f + 1, 0), R-1);
    int y0 = min(max((int)y0f,     0), R-1);
    int y1 = min(max((int)y0f + 1, 0), R-1);
    const unsigned* fb = lds + base + face * R * R;
    uint4 q = make_uint4(fb[y0*R + x0], fb[y0*R + x1],
                         fb[y1*R + x0], fb[y1*R + x1]);
    return q10_blend(q, fx, fy);
}

// ---------- raw f32 bilinear (reference-exact; used for s0 level and fallback) ----------
__device__ __forceinline__ V3 bilinear_cube3(const float* __restrict__ tex, int R,
                                             int face, float u, float v){
    float Rf = (float)R;
    float tu = fmaf(fmaf(u, 0.5f, 0.5f), Rf, -0.5f);
    float tv = fmaf(fmaf(v, 0.5f, 0.5f), Rf, -0.5f);
    float x0 = floorf(tu), y0 = floorf(tv);
    float fx = tu - x0,    fy = tv - y0;
    int x0i = min(max((int)x0,     0), R-1);
    int x1i = min(max((int)x0 + 1, 0), R-1);
    int y0i = min(max((int)y0,     0), R-1);
    int y1i = min(max((int)y0 + 1, 0), R-1);
    const float* base = tex + (size_t)face * R * R * 3;
    const float* r0 = base + (size_t)y0i * R * 3;
    const float* r1 = base + (size_t)y1i * R * 3;
    float a0 = r0[3*x0i], a1 = r0[3*x0i+1], a2 = r0[3*x0i+2];
    float b0 = r0[3*x1i], b1 = r0[3*x1i+1], b2 = r0[3*x1i+2];
    float d0 = r1[3*x0i], d1 = r1[3*x0i+1], d2 = r1[3*x0i+2];
    float e0 = r1[3*x1i], e1 = r1[3*x1i+1], e2 = r1[3*x1i+2];
    float w00 = (1.f-fx)*(1.f-fy), w01 = fx*(1.f-fy);
    float w10 = (1.f-fx)*fy,       w11 = fx*fy;
    V3 out;
    out.x = a0*w00 + b0*w01 + d0*w10 + e0*w11;
    out.y = a1*w00 + b1*w01 + d1*w10 + e1*w11;
    out.z = a2*w00 + b2*w01 + d2*w10 + e2*w11;
    return out;
}

__device__ __forceinline__ void sample_fg(const float* __restrict__ lut,
                                          float u, float v, float& fa, float& fb){
    const int W = 256, H = 256;
    float tu = fmaf(u, (float)W, -0.5f);
    float tv = fmaf(v, (float)H, -0.5f);
    float x0 = floorf(tu), y0 = floorf(tv);
    float fx = tu - x0,    fy = tv - y0;
    int x0i = min(max((int)x0,     0), W-1);
    int x1i = min(max((int)x0 + 1, 0), W-1);
    int y0i = min(max((int)y0,     0), H-1);
    int y1i = min(max((int)y0 + 1, 0), H-1);
    const float2* l2 = (const float2*)lut;
    float2 a = l2[(size_t)y0i*W + x0i];
    float2 b = l2[(size_t)y0i*W + x1i];
    float2 d = l2[(size_t)y1i*W + x0i];
    float2 e = l2[(size_t)y1i*W + x1i];
    float w00 = (1.f-fx)*(1.f-fy), w01 = fx*(1.f-fy);
    float w10 = (1.f-fx)*fy,       w11 = fx*fy;
    fa = a.x*w00 + b.x*w01 + d.x*w10 + e.x*w11;
    fb = a.y*w00 + b.y*w01 + d.y*w10 + e.y*w11;
}

// ---------- linear -> srgb ----------
__device__ __forceinline__ float lin2srgb(float x){
    float xs = (x > 0.0031308f) ? x : 1.0f;
    float p  = __builtin_amdgcn_exp2f(__builtin_amdgcn_logf(xs) * (1.0f/2.4f));
    return (x > 0.0031308f) ? fmaf(1.055f, p, -0.055f) : 12.92f * x;
}

__device__ __forceinline__ float clamp01(float x){ return fminf(fmaxf(x, 0.f), 1.f); }

// ---------- per-pixel precomputed state ----------
struct PixPre {
    V3 diff_alb, spec_alb;
    int sface; float su, sv;
    int dface; float du, dv;
    int offA, RA, offB, RB; float f;
    float ndotv, rough;
};

__device__ __forceinline__ PixPre pre_pixel_v(V3 pos, V3 nrm, V3 bc, float m, float r, V3 vp)
{
    V3 wo = nrm3(v3sub(vp, pos));
    float ndv_raw = dot3(wo, nrm);
    V3 refl = nrm3(v3sub(v3scale(nrm, 2.0f*ndv_raw), wo));

    PixPre p;
    float one_m = 1.0f - m;
    p.diff_alb = v3scale(bc, one_m);
    p.spec_alb = { fmaf(m, bc.x, 0.04f*one_m),
                   fmaf(m, bc.y, 0.04f*one_m),
                   fmaf(m, bc.z, 0.04f*one_m) };
    p.ndotv = fmaxf(ndv_raw, 0.0001f);
    p.rough = r;

    const float MIN_R = 0.08f, MAX_R = 0.5f;
    float lo = (fminf(fmaxf(r, MIN_R), MAX_R) - MIN_R) / (MAX_R - MIN_R) * 4.0f;
    float hi = (fminf(fmaxf(r, MAX_R), 1.0f) - MAX_R) / (1.0f - MAX_R) + 4.0f;
    float mip = (r < MAX_R) ? lo : hi;
    mip = fminf(fmaxf(mip, 0.0f), 5.0f);
    int l0 = min((int)mip, 5);
    p.f = mip - (float)l0;
    int l1 = min(l0 + 1, 5);

    // quad-region base offsets; levels 0 (raw) and 5 (LDS) never read these
    int offA = NOFF1;
    offA = (l0 == 2) ? NOFF2 : offA; offA = (l0 == 3) ? NOFF3 : offA;
    offA = (l0 == 4) ? NOFF4 : offA;
    int offB = NOFF1;
    offB = (l1 == 2) ? NOFF2 : offB; offB = (l1 == 3) ? NOFF3 : offB;
    offB = (l1 == 4) ? NOFF4 : offB;
    p.offA = offA; p.RA = 512 >> l0;
    p.offB = offB; p.RB = 512 >> l1;

    cube_face_uv(nrm, p.dface, p.du, p.dv);
    cube_face_uv(refl, p.sface, p.su, p.sv);
    return p;
}

// ---------- q10 pack helper ----------
__device__ __forceinline__ unsigned pk3(float a, float b, float c){
    unsigned ia = __float2uint_rn(fminf(fmaxf(a, 0.f), 1.f) * 1023.f);
    unsigned ib = __float2uint_rn(fminf(fmaxf(b, 0.f), 1.f) * 1023.f);
    unsigned ic = __float2uint_rn(fminf(fmaxf(c, 0.f), 1.f) * 1023.f);
    return ia | (ib << 10) | (ic << 20);
}

// ---------- vectorized pack: s1..s4 quads + fg quads + appendix; s0 NOT touched ----------
__global__ __launch_bounds__(256)
void pack_q10r(const float* __restrict__ s1, const float* __restrict__ s2,
               const float* __restrict__ s3, const float* __restrict__ s4,
               const float* __restrict__ s5, const float* __restrict__ diffuse,
               const float* __restrict__ fg_lut,
               uint4* __restrict__ qws)
{
    int t = blockIdx.x * blockDim.x + threadIdx.x;
    if (t >= NQ4_TOTAL) return;

    if (t >= NQ4_SPEC + NQ4_FG) {
        int local4 = (t - NQ4_SPEC - NQ4_FG) * 4;
        const float* src; int idx;
        if (local4 < APP_M5) { src = diffuse; idx = local4; }
        else                 { src = s5;      idx = local4 - APP_M5; }
        const float4* sp = (const float4*)(src + 3*idx);
        float4 a = sp[0], b = sp[1], c = sp[2];
        uint4 o;
        o.x = pk3(a.x, a.y, a.z);
        o.y = pk3(a.w, b.x, b.y);
        o.z = pk3(b.z, b.w, c.x);
        o.w = pk3(c.y, c.z, c.w);
        *(uint4*)((unsigned*)(qws + NTOT_QUADS) + local4) = o;
        return;
    }

    if (t >= NQ4_SPEC) {
        int local = (t - NQ4_SPEC) * 4;
        int x = local & 255, y = local >> 8;
        int y1 = (y == 255) ? y : y + 1;
        const float* r0p = fg_lut + 2*local;
        const float* r1p = fg_lut + 2*((y1 << 8) + x);
        bool edge = (x == 252);
        float4 r0a = ((const float4*)r0p)[0], r0b = ((const float4*)r0p)[1];
        float4 r1a = ((const float4*)r1p)[0], r1b = ((const float4*)r1p)[1];
        float4 r0c = *(const float4*)(r0p + (edge ? 4 : 8));
        float4 r1c = *(const float4*)(r1p + (edge ? 4 : 8));
        float a0[5], b0[5], a1[5], b1[5];
        a0[0]=r0a.x; b0[0]=r0a.y; a0[1]=r0a.z; b0[1]=r0a.w;
        a0[2]=r0b.x; b0[2]=r0b.y; a0[3]=r0b.z; b0[3]=r0b.w;
        a0[4]= edge ? r0b.z : r0c.x; b0[4]= edge ? r0b.w : r0c.y;
        a1[0]=r1a.x; b1[0]=r1a.y; a1[1]=r1a.z; b1[1]=r1a.w;
        a1[2]=r1b.x; b1[2]=r1b.y; a1[3]=r1b.z; b1[3]=r1b.w;
        a1[4]= edge ? r1b.z : r1c.x; b1[4]= edge ? r1b.w : r1c.y;
        #pragma unroll
        for (int k = 0; k < 4; ++k) {
            uint4 q;
            q.x = pk3(a0[k], b0[k], a0[k+1]);
            q.y = pk3(b0[k+1], a1[k], b1[k]);
            q.z = pk3(a1[k+1], b1[k+1], 0.f);
            q.w = 0u;
            qws[(size_t)NFG_OFF + local + k] = q;
        }
        return;
    }

    int local4q = t * 4;
    const float* src; int local; int Rm;
    if      (local4q >= NOFF4) { src = s4; local = local4q - NOFF4; Rm = 31;  }
    else if (local4q >= NOFF3) { src = s3; local = local4q - NOFF3; Rm = 63;  }
    else if (local4q >= NOFF2) { src = s2; local = local4q - NOFF2; Rm = 127; }
    else                       { src = s1; local = local4q;         Rm = 255; }
    int x = local & Rm;
    int y = (local / (Rm + 1)) & Rm;
    int rowUp = (y == Rm) ? 0 : (Rm + 1);
    const float* r0p = src + 3*local;
    const float* r1p = src + 3*(local + rowUp);
    bool edge = (x + 4 > Rm);
    float4 A0 = ((const float4*)r0p)[0], A1 = ((const float4*)r0p)[1], A2 = ((const float4*)r0p)[2];
    float4 B0 = ((const float4*)r1p)[0], B1 = ((const float4*)r1p)[1], B2 = ((const float4*)r1p)[2];
    float4 A3 = *(const float4*)(r0p + (edge ? 8 : 12));
    float4 B3 = *(const float4*)(r1p + (edge ? 8 : 12));
    unsigned t0[5], t1[5];
    t0[0] = pk3(A0.x, A0.y, A0.z);
    t0[1] = pk3(A0.w, A1.x, A1.y);
    t0[2] = pk3(A1.z, A1.w, A2.x);
    t0[3] = pk3(A2.y, A2.z, A2.w);
    t0[4] = edge ? t0[3] : pk3(A3.x, A3.y, A3.z);
    t1[0] = pk3(B0.x, B0.y, B0.z);
    t1[1] = pk3(B0.w, B1.x, B1.y);
    t1[2] = pk3(B1.z, B1.w, B2.x);
    t1[3] = pk3(B2.y, B2.z, B2.w);
    t1[4] = edge ? t1[3] : pk3(B3.x, B3.y, B3.z);
    #pragma unroll
    for (int k = 0; k < 4; ++k) {
        uint4 q;
        q.x = t0[k];
        q.y = t0[k+1];
        q.z = t1[k];
        q.w = t1[k+1];
        qws[(size_t)local4q + k] = q;
    }
}

// ---------- spec sampler: raw f32 for s0, LDS for mip5, global quads otherwise ----------
__device__ __forceinline__ V3 sample_spec(const uint4* __restrict__ qws,
                                          const unsigned* lds,
                                          const float* __restrict__ s0raw,
                                          int off, int R, int face, float u, float v){
    if (R == 512)
        return bilinear_cube3(s0raw, 512, face, u, v);
    if (R == 16)
        return lds_bilin(lds, APP_M5, 16, face, u, v);
    int x, y; float fx, fy;
    quad_coord_cube(u, v, R, x, y, fx, fy);
    size_t q = (size_t)off + (size_t)face * R * R + (size_t)y * R + x;
    return q10_blend(qws[q], fx, fy);
}

// ---------- finish one pixel given samples ----------
__device__ __forceinline__ void finish_px(const PixPre& p, uint4 F, float ffx, float ffy,
                                          V3 specA, V3 specB, V3 ambient, float* o){
    float fa, fb;
    q10_fg(F, ffx, ffy, fa, fb);
    V3 spec = { specA.x + (specB.x - specA.x) * p.f,
                specA.y + (specB.y - specA.y) * p.f,
                specA.z + (specB.z - specA.z) * p.f };
    V3 reflc = { fmaf(p.spec_alb.x, fa, fb),
                 fmaf(p.spec_alb.y, fa, fb),
                 fmaf(p.spec_alb.z, fa, fb) };
    V3 rgb = v3add(v3mul(spec, reflc), v3mul(ambient, p.diff_alb));
    o[0] = lin2srgb(clamp01(rgb.x));
    o[1] = lin2srgb(clamp01(rgb.y));
    o[2] = lin2srgb(clamp01(rgb.z));
}

// ---------- main kernel: 2 px/thread, paired issue, NT streaming, LDS small levels ----------
__global__ __launch_bounds__(256)
void envlight_q10h(const float* __restrict__ gb_pos,
                   const float* __restrict__ gb_normal,
                   const float* __restrict__ basecolor,
                   const float* __restrict__ metallic,
                   const float* __restrict__ roughness,
                   const float* __restrict__ view_pos,
                   const float* __restrict__ s0,
                   const uint4* __restrict__ qws,
                   float* __restrict__ out,
                   int n)
{
    __shared__ unsigned lds_small[APP_UINTS];   // 12 KB: diffuse + mip5
    {
        const uint4* app4 = qws + NTOT_QUADS;
        uint4* l4 = (uint4*)lds_small;
        for (int k = threadIdx.x; k < APP_UINTS/4; k += 256)
            l4[k] = app4[k];
    }
    __syncthreads();

    int t = blockIdx.x * blockDim.x + threadIdx.x;
    int i0 = t * 2;
    if (i0 >= n) return;
    V3 vp = { view_pos[0], view_pos[1], view_pos[2] };

    if (i0 + 1 < n) {
        // nontemporal streaming loads (single-use data: keep caches for gathers)
        vf2 p0 = ntload2(gb_pos    + 3*i0), p1 = ntload2(gb_pos    + 3*i0 + 2), p2 = ntload2(gb_pos    + 3*i0 + 4);
        vf2 n0 = ntload2(gb_normal + 3*i0), n1 = ntload2(gb_normal + 3*i0 + 2), n2 = ntload2(gb_normal + 3*i0 + 4);
        vf2 b0 = ntload2(basecolor + 3*i0), b1 = ntload2(basecolor + 3*i0 + 2), b2 = ntload2(basecolor + 3*i0 + 4);
        vf2 mt = ntload2(metallic  + i0);
        vf2 rg = ntload2(roughness + i0);

        // per-pixel state for both pixels first (addresses ready before any gather)
        PixPre pA = pre_pixel_v({p0.x,p0.y,p1.x}, {n0.x,n0.y,n1.x}, {b0.x,b0.y,b1.x},
                                mt.x, rg.x, vp);
        PixPre pB = pre_pixel_v({p1.y,p2.x,p2.y}, {n1.y,n2.x,n2.y}, {b1.y,b2.x,b2.y},
                                mt.y, rg.y, vp);

        // unconditional fg gathers for both pixels — issue first
        int fxA_, fyA_; float fAx, fAy;
        quad_coord_2d(pA.ndotv, pA.rough, 256, 256, fxA_, fyA_, fAx, fAy);
        uint4 FA = qws[(size_t)NFG_OFF + (size_t)fyA_ * 256 + fxA_];
        int fxB_, fyB_; float fBx, fBy;
        quad_coord_2d(pB.ndotv, pB.rough, 256, 256, fxB_, fyB_, fBx, fBy);
        uint4 FB = qws[(size_t)NFG_OFF + (size_t)fyB_ * 256 + fxB_];

        // spec + ambient samples for both pixels
        V3 sAA = sample_spec(qws, lds_small, s0, pA.offA, pA.RA, pA.sface, pA.su, pA.sv);
        V3 sBA = sample_spec(qws, lds_small, s0, pB.offA, pB.RA, pB.sface, pB.su, pB.sv);
        V3 sAB = sample_spec(qws, lds_small, s0, pA.offB, pA.RB, pA.sface, pA.su, pA.sv);
        V3 sBB = sample_spec(qws, lds_small, s0, pB.offB, pB.RB, pB.sface, pB.su, pB.sv);
        V3 amA = lds_bilin(lds_small, APP_DIFF, 16, pA.dface, pA.du, pA.dv);
        V3 amB = lds_bilin(lds_small, APP_DIFF, 16, pB.dface, pB.du, pB.dv);

        float of[6];
        finish_px(pA, FA, fAx, fAy, sAA, sAB, amA, of);
        finish_px(pB, FB, fBx, fBy, sBA, sBB, amB, of + 3);

        ntstore2(out + 3*i0,     of[0], of[1]);
        ntstore2(out + 3*i0 + 2, of[2], of[3]);
        ntstore2(out + 3*i0 + 4, of[4], of[5]);
    } else {
        int i = i0;
        V3 pos = { gb_pos[3*i],    gb_pos[3*i+1],    gb_pos[3*i+2] };
        V3 nrm = { gb_normal[3*i], gb_normal[3*i+1], gb_normal[3*i+2] };
        V3 bc  = { basecolor[3*i], basecolor[3*i+1], basecolor[3*i+2] };
        PixPre pA = pre_pixel_v(pos, nrm, bc, metallic[i], roughness[i], vp);
        int fx_, fy_; float ffx, ffy;
        quad_coord_2d(pA.ndotv, pA.rough, 256, 256, fx_, fy_, ffx, ffy);
        uint4 F = qws[(size_t)NFG_OFF + (size_t)fy_ * 256 + fx_];
        V3 sA = sample_spec(qws, lds_small, s0, pA.offA, pA.RA, pA.sface, pA.su, pA.sv);
        V3 sB = sample_spec(qws, lds_small, s0, pA.offB, pA.RB, pA.sface, pA.su, pA.sv);
        V3 am = lds_bilin(lds_small, APP_DIFF, 16, pA.dface, pA.du, pA.dv);
        float o[3];
        finish_px(pA, F, ffx, ffy, sA, sB, am, o);
        out[3*i+0] = o[0]; out[3*i+1] = o[1]; out[3*i+2] = o[2];
    }
}

// ---------- raw fallback (no workspace) ----------
__global__ __launch_bounds__(256)
void envlight_fallback(const float* __restrict__ gb_pos,
                       const float* __restrict__ gb_normal,
                       const float* __restrict__ basecolor,
                       const float* __restrict__ metallic,
                       const float* __restrict__ roughness,
                       const float* __restrict__ view_pos,
                       const float* __restrict__ diffuse,
                       const float* __restrict__ fg_lut,
                       const float* __restrict__ s0, const float* __restrict__ s1,
                       const float* __restrict__ s2, const float* __restrict__ s3,
                       const float* __restrict__ s4, const float* __restrict__ s5,
                       float* __restrict__ out, int n)
{
    int i = blockIdx.x * blockDim.x + threadIdx.x;
    if (i >= n) return;
    V3 vp = { view_pos[0], view_pos[1], view_pos[2] };
    V3 pos = { gb_pos[3*i],    gb_pos[3*i+1],    gb_pos[3*i+2] };
    V3 nrm = { gb_normal[3*i], gb_normal[3*i+1], gb_normal[3*i+2] };
    V3 bc  = { basecolor[3*i], basecolor[3*i+1], basecolor[3*i+2] };
    PixPre p = pre_pixel_v(pos, nrm, bc, metallic[i], roughness[i], vp);
    int l0 = 0;
    l0 = (p.RA == 256) ? 1 : l0; l0 = (p.RA == 128) ? 2 : l0;
    l0 = (p.RA ==  64) ? 3 : l0; l0 = (p.RA ==  32) ? 4 : l0;
    l0 = (p.RA ==  16) ? 5 : l0;
    int l1 = min(l0 + 1, 5);
    const float* tA = s0;
    tA = (l0 == 1) ? s1 : tA; tA = (l0 == 2) ? s2 : tA;
    tA = (l0 == 3) ? s3 : tA; tA = (l0 == 4) ? s4 : tA; tA = (l0 == 5) ? s5 : tA;
    const float* tB = s0;
    tB = (l1 == 1) ? s1 : tB; tB = (l1 == 2) ? s2 : tB;
    tB = (l1 == 3) ? s3 : tB; tB = (l1 == 4) ? s4 : tB; tB = (l1 == 5) ? s5 : tB;
    V3 ambient = bilinear_cube3(diffuse, 16, p.dface, p.du, p.dv);
    V3 specA   = bilinear_cube3(tA, p.RA, p.sface, p.su, p.sv);
    V3 specB   = bilinear_cube3(tB, p.RB, p.sface, p.su, p.sv);
    float fa, fb;
    sample_fg(fg_lut, p.ndotv, p.rough, fa, fb);
    V3 spec = { specA.x + (specB.x - specA.x) * p.f,
                specA.y + (specB.y - specA.y) * p.f,
                specA.z + (specB.z - specA.z) * p.f };
    V3 reflc = { fmaf(p.spec_alb.x, fa, fb),
                 fmaf(p.spec_alb.y, fa, fb),
                 fmaf(p.spec_alb.z, fa, fb) };
    V3 rgb = v3add(v3mul(spec, reflc), v3mul(ambient, p.diff_alb));
    out[3*i+0] = lin2srgb(clamp01(rgb.x));
    out[3*i+1] = lin2srgb(clamp01(rgb.y));
    out[3*i+2] = lin2srgb(clamp01(rgb.z));
}

extern "C" void kernel_launch(void* const* d_in, const int* in_sizes, int n_in,
                              void* d_out, int out_size, void* d_ws, size_t ws_size,
                              hipStream_t stream) {
    const float* gb_pos    = (const float*)d_in[0];
    const float* gb_normal = (const float*)d_in[1];
    const float* basecolor = (const float*)d_in[2];
    const float* metallic  = (const float*)d_in[3];
    const float* roughness = (const float*)d_in[4];
    const float* view_pos  = (const float*)d_in[5];
    const float* diffuse   = (const float*)d_in[6];
    const float* fg_lut    = (const float*)d_in[7];
    const float* s0        = (const float*)d_in[8];
    const float* s1        = (const float*)d_in[9];
    const float* s2        = (const float*)d_in[10];
    const float* s3        = (const float*)d_in[11];
    const float* s4        = (const float*)d_in[12];
    const float* s5        = (const float*)d_in[13];
    float* out = (float*)d_out;

    int n = in_sizes[0] / 3;
    int block = 256;

    if (ws_size >= WS_BYTES_NEW) {
        uint4* qws = (uint4*)d_ws;
        int pgrid = (NQ4_TOTAL + block - 1) / block;
        pack_q10r<<<pgrid, block, 0, stream>>>(s1, s2, s3, s4, s5,
                                               diffuse, fg_lut, qws);
        int t2 = (n + 1) / 2;
        int mgrid = (t2 + block - 1) / block;
        envlight_q10h<<<mgrid, block, 0, stream>>>(gb_pos, gb_normal, basecolor,
            metallic, roughness, view_pos, s0, qws, out, n);
    } else {
        int grid = (n + block - 1) / block;
        envlight_fallback<<<grid, block, 0, stream>>>(gb_pos, gb_normal, basecolor,
            metallic, roughness, view_pos, diffuse, fg_lut,
            s0, s1, s2, s3, s4, s5, out, n);
    }
}

// Round 7
// 151.053 us; speedup vs baseline: 1.0520x; 1.0043x over previous
//
#include <hip/hip_runtime.h>
#include <hip/hip_fp16.h>

// ---------- small vector helpers ----------
struct V3 { float x, y, z; };

__device__ __forceinline__ V3 v3add(V3 a, V3 b){ return {a.x+b.x, a.y+b.y, a.z+b.z}; }
__device__ __forceinline__ V3 v3sub(V3 a, V3 b){ return {a.x-b.x, a.y-b.y, a.z-b.z}; }
__device__ __forceinline__ V3 v3scale(V3 a, float s){ return {a.x*s, a.y*s, a.z*s}; }
__device__ __forceinline__ V3 v3mul(V3 a, V3 b){ return {a.x*b.x, a.y*b.y, a.z*b.z}; }
__device__ __forceinline__ float dot3(V3 a, V3 b){ return fmaf(a.x,b.x, fmaf(a.y,b.y, a.z*b.z)); }
__device__ __forceinline__ V3 nrm3(V3 a){
    float s = rsqrtf(fmaxf(dot3(a,a), 1e-20f));
    return v3scale(a, s);
}

// nontemporal helpers
typedef float vf2 __attribute__((ext_vector_type(2)));
__device__ __forceinline__ vf2 ntload2(const float* p){
    return __builtin_nontemporal_load((const vf2*)p);
}
__device__ __forceinline__ void ntstore2(float* p, float a, float b){
    vf2 v; v.x = a; v.y = b;
    __builtin_nontemporal_store(v, (vf2*)p);
}

// ---------- layout ----------
// quad region (uint4 per texel, 2x2 footprint): s1..s4 + fg
//   s1 (R=256): [0, 393216)
//   s2 (R=128): [393216, 491520)
//   s3 (R= 64): [491520, 516096)
//   s4 (R= 32): [516096, 522240)
//   fg  (256²): [522240, 587776)
#define NOFF1 0
#define NOFF2 393216
#define NOFF3 491520
#define NOFF4 516096
#define SPEC4_COUNT 522240
#define NFG_OFF 522240
#define NTOT_QUADS 587776
// appendix: compact 1-uint-per-texel q10 for diffuse(1536) + mip5(1536)
#define APP_DIFF 0
#define APP_M5   1536
#define APP_UINTS 3072
// compact s0 region: 1 uint per texel, 6*512*512 = 1,572,864 uints (6.29 MB)
#define CS0_COUNT 1572864
#define WS_BYTES_C ((size_t)NTOT_QUADS * 16 + (size_t)(APP_UINTS + CS0_COUNT) * 4) // 15,708,160

// pack thread counts (4 quads / 4 texels per thread)
#define NQ4_SPEC (SPEC4_COUNT/4)    // 130,560
#define NQ4_FG   (65536/4)          // 16,384
#define NQ4_APP  (APP_UINTS/4)      // 768
#define NQ4_CS0  (CS0_COUNT/4)      // 393,216
#define NQ4_TOTAL (NQ4_SPEC + NQ4_FG + NQ4_APP + NQ4_CS0)   // 540,928

// ---------- cube face / uv ----------
__device__ __forceinline__ void cube_face_uv(V3 d, int& face, float& u, float& v){
    float ax = fabsf(d.x), ay = fabsf(d.y), az = fabsf(d.z);
    bool is_x = (ax >= ay) && (ax >= az);
    bool is_y = (!is_x) && (ay >= az);
    face = is_x ? (d.x >= 0.f ? 0 : 1)
                : (is_y ? (d.y >= 0.f ? 2 : 3)
                        : (d.z >= 0.f ? 4 : 5));
    float ma = fmaxf(is_x ? ax : (is_y ? ay : az), 1e-20f);
    float un = (face == 0) ? -d.z : (face == 1) ? d.z : (face == 5) ? -d.x : d.x;
    float vn = (face == 2) ?  d.z : (face == 3) ? -d.z : -d.y;
    float inv = 1.0f / ma;
    u = un * inv;
    v = vn * inv;
}

// ---------- bilinear coords ----------
__device__ __forceinline__ void quad_coord_cube(float u, float v, int R,
                                                int& xq, int& yq, float& fx, float& fy){
    float Rf = (float)R;
    float tu = fmaf(fmaf(u, 0.5f, 0.5f), Rf, -0.5f);
    float tv = fmaf(fmaf(v, 0.5f, 0.5f), Rf, -0.5f);
    float x0f = floorf(tu), y0f = floorf(tv);
    fx = tu - x0f; fy = tv - y0f;
    int x0 = (int)x0f, y0 = (int)y0f;
    fx = (x0 < 0) ? 0.f : fx;
    fy = (y0 < 0) ? 0.f : fy;
    xq = min(max(x0, 0), R-1);
    yq = min(max(y0, 0), R-1);
}

__device__ __forceinline__ void quad_coord_2d(float u, float v, int W, int H,
                                              int& xq, int& yq, float& fx, float& fy){
    float tu = fmaf(u, (float)W, -0.5f);
    float tv = fmaf(v, (float)H, -0.5f);
    float x0f = floorf(tu), y0f = floorf(tv);
    fx = tu - x0f; fy = tv - y0f;
    int x0 = (int)x0f, y0 = (int)y0f;
    fx = (x0 < 0) ? 0.f : fx;
    fy = (y0 < 0) ? 0.f : fy;
    xq = min(max(x0, 0), W-1);
    yq = min(max(y0, 0), H-1);
}

// ---------- q10 blend (4 packed texels: 00,01,10,11) ----------
__device__ __forceinline__ V3 q10_blend(uint4 q, float fx, float fy){
    float w00 = (1.f-fx)*(1.f-fy), w01 = fx*(1.f-fy);
    float w10 = (1.f-fx)*fy,       w11 = fx*fy;
    float r = (float)(q.x & 1023u)*w00 + (float)(q.y & 1023u)*w01
            + (float)(q.z & 1023u)*w10 + (float)(q.w & 1023u)*w11;
    float g = (float)((q.x>>10) & 1023u)*w00 + (float)((q.y>>10) & 1023u)*w01
            + (float)((q.z>>10) & 1023u)*w10 + (float)((q.w>>10) & 1023u)*w11;
    float b = (float)((q.x>>20) & 1023u)*w00 + (float)((q.y>>20) & 1023u)*w01
            + (float)((q.z>>20) & 1023u)*w10 + (float)((q.w>>20) & 1023u)*w11;
    const float s = 1.0f/1023.0f;
    return { r*s, g*s, b*s };
}

__device__ __forceinline__ void q10_fg(uint4 q, float fx, float fy,
                                       float& fa, float& fb){
    float w00 = (1.f-fx)*(1.f-fy), w01 = fx*(1.f-fy);
    float w10 = (1.f-fx)*fy,       w11 = fx*fy;
    float a00 = (float)(q.x & 1023u),        b00 = (float)((q.x>>10) & 1023u);
    float a01 = (float)((q.x>>20) & 1023u),  b01 = (float)(q.y & 1023u);
    float a10 = (float)((q.y>>10) & 1023u),  b10 = (float)((q.y>>20) & 1023u);
    float a11 = (float)(q.z & 1023u),        b11 = (float)((q.z>>10) & 1023u);
    const float s = 1.0f/1023.0f;
    fa = (a00*w00 + a01*w01 + a10*w10 + a11*w11) * s;
    fb = (b00*w00 + b01*w01 + b10*w10 + b11*w11) * s;
}

// ---------- compact-q10 4-corner bilinear (works for LDS or global base) ----------
__device__ __forceinline__ V3 compact_bilin(const unsigned* __restrict__ tex, int R,
                                            int face, float u, float v){
    float Rf = (float)R;
    float tu = fmaf(fmaf(u, 0.5f, 0.5f), Rf, -0.5f);
    float tv = fmaf(fmaf(v, 0.5f, 0.5f), Rf, -0.5f);
    float x0f = floorf(tu), y0f = floorf(tv);
    float fx = tu - x0f, fy = tv - y0f;
    int x0 = min(max((int)x0f,     0), R-1);
    int x1 = min(max((int)x0f + 1, 0), R-1);
    int y0 = min(max((int)y0f,     0), R-1);
    int y1 = min(max((int)y0f + 1, 0), R-1);
    const unsigned* fb = tex + face * R * R;
    uint4 q = make_uint4(fb[y0*R + x0], fb[y0*R + x1],
                         fb[y1*R + x0], fb[y1*R + x1]);
    // clamped duplicate corners make fx/fy irrelevant at borders
    return q10_blend(q, fx, fy);
}

// ---------- raw f32 bilinear (fallback only) ----------
__device__ __forceinline__ V3 bilinear_cube3(const float* __restrict__ tex, int R,
                                             int face, float u, float v){
    float Rf = (float)R;
    float tu = fmaf(fmaf(u, 0.5f, 0.5f), Rf, -0.5f);
    float tv = fmaf(fmaf(v, 0.5f, 0.5f), Rf, -0.5f);
    float x0 = floorf(tu), y0 = floorf(tv);
    float fx = tu - x0,    fy = tv - y0;
    int x0i = min(max((int)x0,     0), R-1);
    int x1i = min(max((int)x0 + 1, 0), R-1);
    int y0i = min(max((int)y0,     0), R-1);
    int y1i = min(max((int)y0 + 1, 0), R-1);
    const float* base = tex + (size_t)face * R * R * 3;
    const float* r0 = base + (size_t)y0i * R * 3;
    const float* r1 = base + (size_t)y1i * R * 3;
    float a0 = r0[3*x0i], a1 = r0[3*x0i+1], a2 = r0[3*x0i+2];
    float b0 = r0[3*x1i], b1 = r0[3*x1i+1], b2 = r0[3*x1i+2];
    float d0 = r1[3*x0i], d1 = r1[3*x0i+1], d2 = r1[3*x0i+2];
    float e0 = r1[3*x1i], e1 = r1[3*x1i+1], e2 = r1[3*x1i+2];
    float w00 = (1.f-fx)*(1.f-fy), w01 = fx*(1.f-fy);
    float w10 = (1.f-fx)*fy,       w11 = fx*fy;
    V3 out;
    out.x = a0*w00 + b0*w01 + d0*w10 + e0*w11;
    out.y = a1*w00 + b1*w01 + d1*w10 + e1*w11;
    out.z = a2*w00 + b2*w01 + d2*w10 + e2*w11;
    return out;
}

__device__ __forceinline__ void sample_fg(const float* __restrict__ lut,
                                          float u, float v, float& fa, float& fb){
    const int W = 256, H = 256;
    float tu = fmaf(u, (float)W, -0.5f);
    float tv = fmaf(v, (float)H, -0.5f);
    float x0 = floorf(tu), y0 = floorf(tv);
    float fx = tu - x0,    fy = tv - y0;
    int x0i = min(max((int)x0,     0), W-1);
    int x1i = min(max((int)x0 + 1, 0), W-1);
    int y0i = min(max((int)y0,     0), H-1);
    int y1i = min(max((int)y0 + 1, 0), H-1);
    const float2* l2 = (const float2*)lut;
    float2 a = l2[(size_t)y0i*W + x0i];
    float2 b = l2[(size_t)y0i*W + x1i];
    float2 d = l2[(size_t)y1i*W + x0i];
    float2 e = l2[(size_t)y1i*W + x1i];
    float w00 = (1.f-fx)*(1.f-fy), w01 = fx*(1.f-fy);
    float w10 = (1.f-fx)*fy,       w11 = fx*fy;
    fa = a.x*w00 + b.x*w01 + d.x*w10 + e.x*w11;
    fb = a.y*w00 + b.y*w01 + d.y*w10 + e.y*w11;
}

// ---------- linear -> srgb ----------
__device__ __forceinline__ float lin2srgb(float x){
    float xs = (x > 0.0031308f) ? x : 1.0f;
    float p  = __builtin_amdgcn_exp2f(__builtin_amdgcn_logf(xs) * (1.0f/2.4f));
    return (x > 0.0031308f) ? fmaf(1.055f, p, -0.055f) : 12.92f * x;
}

__device__ __forceinline__ float clamp01(float x){ return fminf(fmaxf(x, 0.f), 1.f); }

// ---------- per-pixel precomputed state ----------
struct PixPre {
    V3 diff_alb, spec_alb;
    int sface; float su, sv;
    int dface; float du, dv;
    int offA, RA, offB, RB; float f;
    float ndotv, rough;
};

__device__ __forceinline__ PixPre pre_pixel_v(V3 pos, V3 nrm, V3 bc, float m, float r, V3 vp)
{
    V3 wo = nrm3(v3sub(vp, pos));
    float ndv_raw = dot3(wo, nrm);
    V3 refl = nrm3(v3sub(v3scale(nrm, 2.0f*ndv_raw), wo));

    PixPre p;
    float one_m = 1.0f - m;
    p.diff_alb = v3scale(bc, one_m);
    p.spec_alb = { fmaf(m, bc.x, 0.04f*one_m),
                   fmaf(m, bc.y, 0.04f*one_m),
                   fmaf(m, bc.z, 0.04f*one_m) };
    p.ndotv = fmaxf(ndv_raw, 0.0001f);
    p.rough = r;

    const float MIN_R = 0.08f, MAX_R = 0.5f;
    float lo = (fminf(fmaxf(r, MIN_R), MAX_R) - MIN_R) / (MAX_R - MIN_R) * 4.0f;
    float hi = (fminf(fmaxf(r, MAX_R), 1.0f) - MAX_R) / (1.0f - MAX_R) + 4.0f;
    float mip = (r < MAX_R) ? lo : hi;
    mip = fminf(fmaxf(mip, 0.0f), 5.0f);
    int l0 = min((int)mip, 5);
    p.f = mip - (float)l0;
    int l1 = min(l0 + 1, 5);

    // quad-region base offsets; levels 0 (compact-s0) and 5 (LDS) never read these
    int offA = NOFF1;
    offA = (l0 == 2) ? NOFF2 : offA; offA = (l0 == 3) ? NOFF3 : offA;
    offA = (l0 == 4) ? NOFF4 : offA;
    int offB = NOFF1;
    offB = (l1 == 2) ? NOFF2 : offB; offB = (l1 == 3) ? NOFF3 : offB;
    offB = (l1 == 4) ? NOFF4 : offB;
    p.offA = offA; p.RA = 512 >> l0;
    p.offB = offB; p.RB = 512 >> l1;

    cube_face_uv(nrm, p.dface, p.du, p.dv);
    cube_face_uv(refl, p.sface, p.su, p.sv);
    return p;
}

// ---------- q10 pack helper ----------
__device__ __forceinline__ unsigned pk3(float a, float b, float c){
    unsigned ia = __float2uint_rn(fminf(fmaxf(a, 0.f), 1.f) * 1023.f);
    unsigned ib = __float2uint_rn(fminf(fmaxf(b, 0.f), 1.f) * 1023.f);
    unsigned ic = __float2uint_rn(fminf(fmaxf(c, 0.f), 1.f) * 1023.f);
    return ia | (ib << 10) | (ic << 20);
}

// ---------- pack: s1..s4 quads + fg quads + appendix + compact s0 ----------
__global__ __launch_bounds__(256)
void pack_q10c(const float* __restrict__ s0,
               const float* __restrict__ s1, const float* __restrict__ s2,
               const float* __restrict__ s3, const float* __restrict__ s4,
               const float* __restrict__ s5, const float* __restrict__ diffuse,
               const float* __restrict__ fg_lut,
               uint4* __restrict__ qws)
{
    int t = blockIdx.x * blockDim.x + threadIdx.x;
    if (t >= NQ4_TOTAL) return;

    if (t >= NQ4_SPEC + NQ4_FG + NQ4_APP) {
        // compact s0: 4 texels per thread, coalesced float4 in / uint4 out
        int local4 = (t - NQ4_SPEC - NQ4_FG - NQ4_APP) * 4;
        const float4* sp = (const float4*)(s0 + 3*local4);
        float4 a = sp[0], b = sp[1], c = sp[2];
        uint4 o;
        o.x = pk3(a.x, a.y, a.z);
        o.y = pk3(a.w, b.x, b.y);
        o.z = pk3(b.z, b.w, c.x);
        o.w = pk3(c.y, c.z, c.w);
        unsigned* cs0 = (unsigned*)(qws + NTOT_QUADS) + APP_UINTS;
        *(uint4*)(cs0 + local4) = o;
        return;
    }

    if (t >= NQ4_SPEC + NQ4_FG) {
        // appendix: 4 compact texels (diffuse then mip5)
        int local4 = (t - NQ4_SPEC - NQ4_FG) * 4;
        const float* src; int idx;
        if (local4 < APP_M5) { src = diffuse; idx = local4; }
        else                 { src = s5;      idx = local4 - APP_M5; }
        const float4* sp = (const float4*)(src + 3*idx);
        float4 a = sp[0], b = sp[1], c = sp[2];
        uint4 o;
        o.x = pk3(a.x, a.y, a.z);
        o.y = pk3(a.w, b.x, b.y);
        o.z = pk3(b.z, b.w, c.x);
        o.w = pk3(c.y, c.z, c.w);
        *(uint4*)((unsigned*)(qws + NTOT_QUADS) + local4) = o;
        return;
    }

    if (t >= NQ4_SPEC) {
        // fg region: 4 quads along a row
        int local = (t - NQ4_SPEC) * 4;
        int x = local & 255, y = local >> 8;
        int y1 = (y == 255) ? y : y + 1;
        const float* r0p = fg_lut + 2*local;
        const float* r1p = fg_lut + 2*((y1 << 8) + x);
        bool edge = (x == 252);
        float4 r0a = ((const float4*)r0p)[0], r0b = ((const float4*)r0p)[1];
        float4 r1a = ((const float4*)r1p)[0], r1b = ((const float4*)r1p)[1];
        float4 r0c = *(const float4*)(r0p + (edge ? 4 : 8));
        float4 r1c = *(const float4*)(r1p + (edge ? 4 : 8));
        float a0[5], b0[5], a1[5], b1[5];
        a0[0]=r0a.x; b0[0]=r0a.y; a0[1]=r0a.z; b0[1]=r0a.w;
        a0[2]=r0b.x; b0[2]=r0b.y; a0[3]=r0b.z; b0[3]=r0b.w;
        a0[4]= edge ? r0b.z : r0c.x; b0[4]= edge ? r0b.w : r0c.y;
        a1[0]=r1a.x; b1[0]=r1a.y; a1[1]=r1a.z; b1[1]=r1a.w;
        a1[2]=r1b.x; b1[2]=r1b.y; a1[3]=r1b.z; b1[3]=r1b.w;
        a1[4]= edge ? r1b.z : r1c.x; b1[4]= edge ? r1b.w : r1c.y;
        #pragma unroll
        for (int k = 0; k < 4; ++k) {
            uint4 q;
            q.x = pk3(a0[k], b0[k], a0[k+1]);
            q.y = pk3(b0[k+1], a1[k], b1[k]);
            q.z = pk3(a1[k+1], b1[k+1], 0.f);
            q.w = 0u;
            qws[(size_t)NFG_OFF + local + k] = q;
        }
        return;
    }

    // spec quad region (s1..s4): 4 quads along a row
    int local4q = t * 4;
    const float* src; int local; int Rm;
    if      (local4q >= NOFF4) { src = s4; local = local4q - NOFF4; Rm = 31;  }
    else if (local4q >= NOFF3) { src = s3; local = local4q - NOFF3; Rm = 63;  }
    else if (local4q >= NOFF2) { src = s2; local = local4q - NOFF2; Rm = 127; }
    else                       { src = s1; local = local4q;         Rm = 255; }
    int x = local & Rm;
    int y = (local / (Rm + 1)) & Rm;
    int rowUp = (y == Rm) ? 0 : (Rm + 1);
    const float* r0p = src + 3*local;
    const float* r1p = src + 3*(local + rowUp);
    bool edge = (x + 4 > Rm);
    float4 A0 = ((const float4*)r0p)[0], A1 = ((const float4*)r0p)[1], A2 = ((const float4*)r0p)[2];
    float4 B0 = ((const float4*)r1p)[0], B1 = ((const float4*)r1p)[1], B2 = ((const float4*)r1p)[2];
    float4 A3 = *(const float4*)(r0p + (edge ? 8 : 12));
    float4 B3 = *(const float4*)(r1p + (edge ? 8 : 12));
    unsigned t0[5], t1[5];
    t0[0] = pk3(A0.x, A0.y, A0.z);
    t0[1] = pk3(A0.w, A1.x, A1.y);
    t0[2] = pk3(A1.z, A1.w, A2.x);
    t0[3] = pk3(A2.y, A2.z, A2.w);
    t0[4] = edge ? t0[3] : pk3(A3.x, A3.y, A3.z);
    t1[0] = pk3(B0.x, B0.y, B0.z);
    t1[1] = pk3(B0.w, B1.x, B1.y);
    t1[2] = pk3(B1.z, B1.w, B2.x);
    t1[3] = pk3(B2.y, B2.z, B2.w);
    t1[4] = edge ? t1[3] : pk3(B3.x, B3.y, B3.z);
    #pragma unroll
    for (int k = 0; k < 4; ++k) {
        uint4 q;
        q.x = t0[k];
        q.y = t0[k+1];
        q.z = t1[k];
        q.w = t1[k+1];
        qws[(size_t)local4q + k] = q;
    }
}

// ---------- spec sampler: compact-global for s0, LDS for mip5, quads otherwise ----------
__device__ __forceinline__ V3 sample_spec(const uint4* __restrict__ qws,
                                          const unsigned* lds,
                                          const unsigned* __restrict__ cs0,
                                          int off, int R, int face, float u, float v){
    if (R == 512)
        return compact_bilin(cs0, 512, face, u, v);
    if (R == 16)
        return compact_bilin(lds + APP_M5, 16, face, u, v);
    int x, y; float fx, fy;
    quad_coord_cube(u, v, R, x, y, fx, fy);
    size_t q = (size_t)off + (size_t)face * R * R + (size_t)y * R + x;
    return q10_blend(qws[q], fx, fy);
}

// ---------- finish one pixel given samples ----------
__device__ __forceinline__ void finish_px(const PixPre& p, uint4 F, float ffx, float ffy,
                                          V3 specA, V3 specB, V3 ambient, float* o){
    float fa, fb;
    q10_fg(F, ffx, ffy, fa, fb);
    V3 spec = { specA.x + (specB.x - specA.x) * p.f,
                specA.y + (specB.y - specA.y) * p.f,
                specA.z + (specB.z - specA.z) * p.f };
    V3 reflc = { fmaf(p.spec_alb.x, fa, fb),
                 fmaf(p.spec_alb.y, fa, fb),
                 fmaf(p.spec_alb.z, fa, fb) };
    V3 rgb = v3add(v3mul(spec, reflc), v3mul(ambient, p.diff_alb));
    o[0] = lin2srgb(clamp01(rgb.x));
    o[1] = lin2srgb(clamp01(rgb.y));
    o[2] = lin2srgb(clamp01(rgb.z));
}

// ---------- main kernel: 2 px/thread, compact s0, NT streaming, LDS small levels ----------
__global__ __launch_bounds__(256)
void envlight_q10c(const float* __restrict__ gb_pos,
                   const float* __restrict__ gb_normal,
                   const float* __restrict__ basecolor,
                   const float* __restrict__ metallic,
                   const float* __restrict__ roughness,
                   const float* __restrict__ view_pos,
                   const uint4* __restrict__ qws,
                   float* __restrict__ out,
                   int n)
{
    __shared__ unsigned lds_small[APP_UINTS];   // 12 KB: diffuse + mip5
    {
        const uint4* app4 = qws + NTOT_QUADS;
        uint4* l4 = (uint4*)lds_small;
        for (int k = threadIdx.x; k < APP_UINTS/4; k += 256)
            l4[k] = app4[k];
    }
    __syncthreads();
    const unsigned* cs0 = (const unsigned*)(qws + NTOT_QUADS) + APP_UINTS;

    int t = blockIdx.x * blockDim.x + threadIdx.x;
    int i0 = t * 2;
    if (i0 >= n) return;
    V3 vp = { view_pos[0], view_pos[1], view_pos[2] };

    if (i0 + 1 < n) {
        // nontemporal streaming loads (single-use data: keep caches for gathers)
        vf2 p0 = ntload2(gb_pos    + 3*i0), p1 = ntload2(gb_pos    + 3*i0 + 2), p2 = ntload2(gb_pos    + 3*i0 + 4);
        vf2 n0 = ntload2(gb_normal + 3*i0), n1 = ntload2(gb_normal + 3*i0 + 2), n2 = ntload2(gb_normal + 3*i0 + 4);
        vf2 b0 = ntload2(basecolor + 3*i0), b1 = ntload2(basecolor + 3*i0 + 2), b2 = ntload2(basecolor + 3*i0 + 4);
        vf2 mt = ntload2(metallic  + i0);
        vf2 rg = ntload2(roughness + i0);

        PixPre pA = pre_pixel_v({p0.x,p0.y,p1.x}, {n0.x,n0.y,n1.x}, {b0.x,b0.y,b1.x},
                                mt.x, rg.x, vp);
        PixPre pB = pre_pixel_v({p1.y,p2.x,p2.y}, {n1.y,n2.x,n2.y}, {b1.y,b2.x,b2.y},
                                mt.y, rg.y, vp);

        // fg gathers for both pixels — issue first
        int fxA_, fyA_; float fAx, fAy;
        quad_coord_2d(pA.ndotv, pA.rough, 256, 256, fxA_, fyA_, fAx, fAy);
        uint4 FA = qws[(size_t)NFG_OFF + (size_t)fyA_ * 256 + fxA_];
        int fxB_, fyB_; float fBx, fBy;
        quad_coord_2d(pB.ndotv, pB.rough, 256, 256, fxB_, fyB_, fBx, fBy);
        uint4 FB = qws[(size_t)NFG_OFF + (size_t)fyB_ * 256 + fxB_];

        // spec + ambient samples for both pixels
        V3 sAA = sample_spec(qws, lds_small, cs0, pA.offA, pA.RA, pA.sface, pA.su, pA.sv);
        V3 sBA = sample_spec(qws, lds_small, cs0, pB.offA, pB.RA, pB.sface, pB.su, pB.sv);
        V3 sAB = sample_spec(qws, lds_small, cs0, pA.offB, pA.RB, pA.sface, pA.su, pA.sv);
        V3 sBB = sample_spec(qws, lds_small, cs0, pB.offB, pB.RB, pB.sface, pB.su, pB.sv);
        V3 amA = compact_bilin(lds_small + APP_DIFF, 16, pA.dface, pA.du, pA.dv);
        V3 amB = compact_bilin(lds_small + APP_DIFF, 16, pB.dface, pB.du, pB.dv);

        float of[6];
        finish_px(pA, FA, fAx, fAy, sAA, sAB, amA, of);
        finish_px(pB, FB, fBx, fBy, sBA, sBB, amB, of + 3);

        ntstore2(out + 3*i0,     of[0], of[1]);
        ntstore2(out + 3*i0 + 2, of[2], of[3]);
        ntstore2(out + 3*i0 + 4, of[4], of[5]);
    } else {
        int i = i0;
        V3 pos = { gb_pos[3*i],    gb_pos[3*i+1],    gb_pos[3*i+2] };
        V3 nrm = { gb_normal[3*i], gb_normal[3*i+1], gb_normal[3*i+2] };
        V3 bc  = { basecolor[3*i], basecolor[3*i+1], basecolor[3*i+2] };
        PixPre pA = pre_pixel_v(pos, nrm, bc, metallic[i], roughness[i], vp);
        int fx_, fy_; float ffx, ffy;
        quad_coord_2d(pA.ndotv, pA.rough, 256, 256, fx_, fy_, ffx, ffy);
        uint4 F = qws[(size_t)NFG_OFF + (size_t)fy_ * 256 + fx_];
        V3 sA = sample_spec(qws, lds_small, cs0, pA.offA, pA.RA, pA.sface, pA.su, pA.sv);
        V3 sB = sample_spec(qws, lds_small, cs0, pA.offB, pA.RB, pA.sface, pA.su, pA.sv);
        V3 am = compact_bilin(lds_small + APP_DIFF, 16, pA.dface, pA.du, pA.dv);
        float o[3];
        finish_px(pA, F, ffx, ffy, sA, sB, am, o);
        out[3*i+0] = o[0]; out[3*i+1] = o[1]; out[3*i+2] = o[2];
    }
}

// ---------- raw fallback (no workspace) ----------
__global__ __launch_bounds__(256)
void envlight_fallback(const float* __restrict__ gb_pos,
                       const float* __restrict__ gb_normal,
                       const float* __restrict__ basecolor,
                       const float* __restrict__ metallic,
                       const float* __restrict__ roughness,
                       const float* __restrict__ view_pos,
                       const float* __restrict__ diffuse,
                       const float* __restrict__ fg_lut,
                       const float* __restrict__ s0, const float* __restrict__ s1,
                       const float* __restrict__ s2, const float* __restrict__ s3,
                       const float* __restrict__ s4, const float* __restrict__ s5,
                       float* __restrict__ out, int n)
{
    int i = blockIdx.x * blockDim.x + threadIdx.x;
    if (i >= n) return;
    V3 vp = { view_pos[0], view_pos[1], view_pos[2] };
    V3 pos = { gb_pos[3*i],    gb_pos[3*i+1],    gb_pos[3*i+2] };
    V3 nrm = { gb_normal[3*i], gb_normal[3*i+1], gb_normal[3*i+2] };
    V3 bc  = { basecolor[3*i], basecolor[3*i+1], basecolor[3*i+2] };
    PixPre p = pre_pixel_v(pos, nrm, bc, metallic[i], roughness[i], vp);
    int l0 = 0;
    l0 = (p.RA == 256) ? 1 : l0; l0 = (p.RA == 128) ? 2 : l0;
    l0 = (p.RA ==  64) ? 3 : l0; l0 = (p.RA ==  32) ? 4 : l0;
    l0 = (p.RA ==  16) ? 5 : l0;
    int l1 = min(l0 + 1, 5);
    const float* tA = s0;
    tA = (l0 == 1) ? s1 : tA; tA = (l0 == 2) ? s2 : tA;
    tA = (l0 == 3) ? s3 : tA; tA = (l0 == 4) ? s4 : tA; tA = (l0 == 5) ? s5 : tA;
    const float* tB = s0;
    tB = (l1 == 1) ? s1 : tB; tB = (l1 == 2) ? s2 : tB;
    tB = (l1 == 3) ? s3 : tB; tB = (l1 == 4) ? s4 : tB; tB = (l1 == 5) ? s5 : tB;
    V3 ambient = bilinear_cube3(diffuse, 16, p.dface, p.du, p.dv);
    V3 specA   = bilinear_cube3(tA, p.RA, p.sface, p.su, p.sv);
    V3 specB   = bilinear_cube3(tB, p.RB, p.sface, p.su, p.sv);
    float fa, fb;
    sample_fg(fg_lut, p.ndotv, p.rough, fa, fb);
    V3 spec = { specA.x + (specB.x - specA.x) * p.f,
                specA.y + (specB.y - specA.y) * p.f,
                specA.z + (specB.z - specA.z) * p.f };
    V3 reflc = { fmaf(p.spec_alb.x, fa, fb),
                 fmaf(p.spec_alb.y, fa, fb),
                 fmaf(p.spec_alb.z, fa, fb) };
    V3 rgb = v3add(v3mul(spec, reflc), v3mul(ambient, p.diff_alb));
    out[3*i+0] = lin2srgb(clamp01(rgb.x));
    out[3*i+1] = lin2srgb(clamp01(rgb.y));
    out[3*i+2] = lin2srgb(clamp01(rgb.z));
}

extern "C" void kernel_launch(void* const* d_in, const int* in_sizes, int n_in,
                              void* d_out, int out_size, void* d_ws, size_t ws_size,
                              hipStream_t stream) {
    const float* gb_pos    = (const float*)d_in[0];
    const float* gb_normal = (const float*)d_in[1];
    const float* basecolor = (const float*)d_in[2];
    const float* metallic  = (const float*)d_in[3];
    const float* roughness = (const float*)d_in[4];
    const float* view_pos  = (const float*)d_in[5];
    const float* diffuse   = (const float*)d_in[6];
    const float* fg_lut    = (const float*)d_in[7];
    const float* s0        = (const float*)d_in[8];
    const float* s1        = (const float*)d_in[9];
    const float* s2        = (const float*)d_in[10];
    const float* s3        = (const float*)d_in[11];
    const float* s4        = (const float*)d_in[12];
    const float* s5        = (const float*)d_in[13];
    float* out = (float*)d_out;

    int n = in_sizes[0] / 3;
    int block = 256;

    if (ws_size >= WS_BYTES_C) {
        uint4* qws = (uint4*)d_ws;
        int pgrid = (NQ4_TOTAL + block - 1) / block;
        pack_q10c<<<pgrid, block, 0, stream>>>(s0, s1, s2, s3, s4, s5,
                                               diffuse, fg_lut, qws);
        int t2 = (n + 1) / 2;
        int mgrid = (t2 + block - 1) / block;
        envlight_q10c<<<mgrid, block, 0, stream>>>(gb_pos, gb_normal, basecolor,
            metallic, roughness, view_pos, qws, out, n);
    } else {
        int grid = (n + block - 1) / block;
        envlight_fallback<<<grid, block, 0, stream>>>(gb_pos, gb_normal, basecolor,
            metallic, roughness, view_pos, diffuse, fg_lut,
            s0, s1, s2, s3, s4, s5, out, n);
    }
}